// Round 1
// baseline (4502.150 us; speedup 1.0000x reference)
//
#include <hip/hip_runtime.h>
#include <math.h>

#define Bb 64
#define Nn 4096
#define INDIM 2
#define Uu 64
#define Ff 66                    // INDIM + U
#define RL 4224                  // Ff * Bb, row length of the SpMM feature matrices
#define NU (Nn*Uu)               // 262144
#define MATSZ ((size_t)Nn*(size_t)RL)   // 17,301,504 floats per matrix
#define CAP 524288               // CSR capacity (expected nnz ~344k total)

// ---------------- CSR build from dense supports ----------------
__global__ __launch_bounds__(256) void k_count(const float* __restrict__ sup, int* __restrict__ cnt) {
  const int lane = threadIdx.x & 63;
  const int row = blockIdx.x * 4 + (threadIdx.x >> 6);      // row in [0, 8192): s*4096 + n
  const float* rp = sup + (size_t)row * Nn;
  int c = 0;
  for (int j = lane; j < Nn; j += 64) c += (rp[j] != 0.0f) ? 1 : 0;
  for (int off = 32; off > 0; off >>= 1) c += __shfl_down(c, off, 64);
  if (lane == 0) cnt[row] = c;
}

__global__ __launch_bounds__(1024) void k_scan(const int* __restrict__ cnt, int* __restrict__ ptr) {
  __shared__ int sums[1024];
  const int t = threadIdx.x;
  int loc[8]; int s = 0;
  for (int i = 0; i < 8; ++i) { loc[i] = cnt[t*8+i]; s += loc[i]; }
  sums[t] = s;
  __syncthreads();
  for (int off = 1; off < 1024; off <<= 1) {
    int v = (t >= off) ? sums[t-off] : 0;
    __syncthreads();
    sums[t] += v;
    __syncthreads();
  }
  int ex = (t == 0) ? 0 : sums[t-1];
  for (int i = 0; i < 8; ++i) { ptr[t*8+i] = ex; ex += loc[i]; }
  if (t == 1023) ptr[8192] = ex;
}

__global__ __launch_bounds__(256) void k_fill(const float* __restrict__ sup, const int* __restrict__ ptr,
                                              int* __restrict__ cidx, float* __restrict__ cval) {
  const int lane = threadIdx.x & 63;
  const int row = blockIdx.x * 4 + (threadIdx.x >> 6);
  const float* rp = sup + (size_t)row * Nn;
  const int base = ptr[row];
  const unsigned long long lt = (1ull << lane) - 1ull;
  int off = 0;
  for (int j0 = 0; j0 < Nn; j0 += 64) {
    float v = rp[j0 + lane];
    unsigned long long m = __ballot(v != 0.0f);
    if (v != 0.0f) {
      int pos = base + off + (int)__popcll(m & lt);
      cidx[pos] = j0 + lane;
      cval[pos] = v;
    }
    off += (int)__popcll(m);
  }
}

// ---------------- x0 = [inputs | hx] in [n][b][f] layout ----------------
__global__ __launch_bounds__(256) void k_build_x0(const float* __restrict__ inp, const float* __restrict__ hx,
                                                  float* __restrict__ x0) {
  const int n = blockIdx.x;
  for (int idx = threadIdx.x; idx < RL; idx += 256) {
    const int b = idx / Ff, f = idx - b*Ff;
    float v = (f < INDIM) ? inp[(size_t)b*(size_t)(Nn*INDIM) + (size_t)n*INDIM + f]
                          : hx[(size_t)b*(size_t)NU + (size_t)n*Uu + (f - INDIM)];
    x0[(size_t)n*RL + idx] = v;
  }
}

// ---------------- LDS-staged SpMM: y = A @ x  (PASS2: y = 2*A@x - xsub) ----------------
// Each block owns an 8-float column slab of the 4224-wide matrix, stages all 4096 rows
// (128 KiB LDS), then walks every output row's CSR list reading operands from LDS.
template<bool PASS2>
__global__ __launch_bounds__(256,1) void k_spmm(const float* __restrict__ xin, const float* __restrict__ xsub,
                                                float* __restrict__ yout,
                                                const int* __restrict__ rptr, const int* __restrict__ cidx,
                                                const float* __restrict__ cval) {
  extern __shared__ float slab[];               // [4096][8]
  const int cb = blockIdx.x, s = blockIdx.y;
  const int c0 = cb * 8;
  const float* xi = xin + (PASS2 ? (size_t)s * MATSZ : (size_t)0);
  float* yo = yout + (size_t)s * MATSZ;
  {
    const int k4 = (threadIdx.x & 1) * 4;
    const int jj = threadIdx.x >> 1;
    for (int j0 = 0; j0 < Nn; j0 += 128) {
      const int j = j0 + jj;
      *(float4*)&slab[j*8 + k4] = *(const float4*)&xi[(size_t)j*RL + c0 + k4];
    }
  }
  __syncthreads();
  const int tc = (threadIdx.x & 1) * 4;
  const int tr = threadIdx.x >> 1;
  const int rb = s * Nn;
  for (int r0 = 0; r0 < Nn; r0 += 128) {
    const int row = r0 + tr;
    int p = rptr[rb + row];
    const int p1 = rptr[rb + row + 1];
    float a0 = 0.f, a1 = 0.f, a2 = 0.f, a3 = 0.f;
    // 4-wide chunks: batch the CSR loads so ds_reads pipeline (hide LDS latency at 1 wave/SIMD)
    for (; p + 4 <= p1; p += 4) {
      const int j0 = cidx[p], j1 = cidx[p+1], j2 = cidx[p+2], j3 = cidx[p+3];
      const float b0 = cval[p], b1 = cval[p+1], b2 = cval[p+2], b3 = cval[p+3];
      const float* s0 = &slab[j0*8 + tc];
      const float* s1 = &slab[j1*8 + tc];
      const float* s2 = &slab[j2*8 + tc];
      const float* s3 = &slab[j3*8 + tc];
      a0 += b0*s0[0]; a1 += b0*s0[1]; a2 += b0*s0[2]; a3 += b0*s0[3];
      a0 += b1*s1[0]; a1 += b1*s1[1]; a2 += b1*s1[2]; a3 += b1*s1[3];
      a0 += b2*s2[0]; a1 += b2*s2[1]; a2 += b2*s2[2]; a3 += b2*s2[3];
      a0 += b3*s3[0]; a1 += b3*s3[1]; a2 += b3*s3[2]; a3 += b3*s3[3];
    }
    for (; p < p1; ++p) {
      const int j = cidx[p]; const float b = cval[p];
      const float* sp = &slab[j*8 + tc];
      a0 += b*sp[0]; a1 += b*sp[1]; a2 += b*sp[2]; a3 += b*sp[3];
    }
    const size_t o = (size_t)row*RL + c0 + tc;
    if (PASS2) {
      const float4 xv = *(const float4*)&xsub[o];
      *(float4*)&yo[o] = make_float4(2.f*a0 - xv.x, 2.f*a1 - xv.y, 2.f*a2 - xv.z, 2.f*a3 - xv.w);
    } else {
      *(float4*)&yo[o] = make_float4(a0, a1, a2, a3);
    }
  }
}

// ---------------- per-n output GEMM for gconv1 (O=128), fused sigmoid + r*hx + u store ----------------
// Writes r*hx straight into x0's state slots (the next gconv's input) — no rebuild pass.
__global__ __launch_bounds__(256) void k_gemm1(const float* __restrict__ x0, const float* __restrict__ y1,
                                               const float* __restrict__ y2, const float* __restrict__ W,
                                               const float* __restrict__ bias, const float* __restrict__ hx,
                                               float* __restrict__ x0w, float* __restrict__ ubuf) {
  __shared__ float Xs[RL];                         // one mat row: 16.9 KiB
  const int n = blockIdx.x;
  const int t = threadIdx.x;
  const int tx = t & 31, ty = t >> 5;              // o = tx*4, b = ty*8..+8
  float acc[8][4] = {{0.f}};
  for (int m = 0; m < 5; ++m) {                    // xs order: x0, A0x, (2A0A0-I)x, A1x, (2A1A1-I)x
    const float* mp;
    if (m == 0) mp = x0;
    else { mp = (m & 1) ? y1 : y2; if (m >= 3) mp += MATSZ; }
    mp += (size_t)n * RL;
    __syncthreads();
    for (int i = t; i < RL; i += 256) Xs[i] = mp[i];
    __syncthreads();
    for (int f = 0; f < Ff; ++f) {
      const float4 wv = *(const float4*)&W[(size_t)(f*5+m)*128 + tx*4];
      #pragma unroll
      for (int i = 0; i < 8; ++i) {
        const float xv = Xs[(ty*8+i)*Ff + f];
        acc[i][0] += xv*wv.x; acc[i][1] += xv*wv.y; acc[i][2] += xv*wv.z; acc[i][3] += xv*wv.w;
      }
    }
  }
  #pragma unroll
  for (int i = 0; i < 8; ++i) {
    const int b = ty*8 + i;
    #pragma unroll
    for (int k = 0; k < 4; ++k) {
      const int o = tx*4 + k;
      const float v = acc[i][k] + bias[o];
      const float sg = 1.0f / (1.0f + expf(-v));
      if (o < Uu) {                                 // r gate -> r*hx into x0 state slot
        const float h = hx[(size_t)b*NU + (size_t)n*Uu + o];
        x0w[(size_t)n*RL + b*Ff + INDIM + o] = sg * h;
      } else {                                      // u gate -> stash for final combine
        ubuf[(size_t)b*NU + (size_t)n*Uu + (o - Uu)] = sg;
      }
    }
  }
}

// ---------------- per-n output GEMM for gconv2 (O=64), fused tanh + final gate ----------------
__global__ __launch_bounds__(256) void k_gemm2(const float* __restrict__ x0, const float* __restrict__ y1,
                                               const float* __restrict__ y2, const float* __restrict__ W,
                                               const float* __restrict__ bias, const float* __restrict__ hx,
                                               const float* __restrict__ ubuf, float* __restrict__ out) {
  __shared__ float Xs[RL];
  const int n = blockIdx.x;
  const int t = threadIdx.x;
  const int tx = t & 15, ty = t >> 4;              // o = tx*4, b = ty*4..+4
  float acc[4][4] = {{0.f}};
  for (int m = 0; m < 5; ++m) {
    const float* mp;
    if (m == 0) mp = x0;
    else { mp = (m & 1) ? y1 : y2; if (m >= 3) mp += MATSZ; }
    mp += (size_t)n * RL;
    __syncthreads();
    for (int i = t; i < RL; i += 256) Xs[i] = mp[i];
    __syncthreads();
    for (int f = 0; f < Ff; ++f) {
      const float4 wv = *(const float4*)&W[(size_t)(f*5+m)*64 + tx*4];
      #pragma unroll
      for (int i = 0; i < 4; ++i) {
        const float xv = Xs[(ty*4+i)*Ff + f];
        acc[i][0] += xv*wv.x; acc[i][1] += xv*wv.y; acc[i][2] += xv*wv.z; acc[i][3] += xv*wv.w;
      }
    }
  }
  #pragma unroll
  for (int i = 0; i < 4; ++i) {
    const int b = ty*4 + i;
    #pragma unroll
    for (int k = 0; k < 4; ++k) {
      const int o = tx*4 + k;
      const float c = tanhf(acc[i][k] + bias[o]);
      const size_t ix = (size_t)b*NU + (size_t)n*Uu + o;
      const float u = ubuf[ix];
      const float h = hx[ix];
      out[ix] = u*h + (1.0f - u)*c;
    }
  }
}

extern "C" void kernel_launch(void* const* d_in, const int* in_sizes, int n_in,
                              void* d_out, int out_size, void* d_ws, size_t ws_size,
                              hipStream_t stream) {
  const float* inp = (const float*)d_in[0];
  const float* hx  = (const float*)d_in[1];
  const float* sup = (const float*)d_in[2];
  const float* ruW = (const float*)d_in[3];
  const float* ruB = (const float*)d_in[4];
  const float* gW  = (const float*)d_in[5];
  const float* gB  = (const float*)d_in[6];
  float* out = (float*)d_out;

  // workspace layout (~418 MB): x0 | y1[2] | y2[2] | u | CSR
  float* ws   = (float*)d_ws;
  float* x0   = ws;
  float* y1   = x0 + MATSZ;
  float* y2   = y1 + 2*MATSZ;
  float* ubuf = y2 + 2*MATSZ;
  int*   rcnt = (int*)(ubuf + (size_t)Bb*NU);
  int*   rptr = rcnt + 8192;
  int*   cidx = rptr + 8200;                 // 8193 rounded up for alignment
  float* cval = (float*)(cidx + CAP);

  hipFuncSetAttribute(reinterpret_cast<const void*>(&k_spmm<false>),
                      hipFuncAttributeMaxDynamicSharedMemorySize, 131072);
  hipFuncSetAttribute(reinterpret_cast<const void*>(&k_spmm<true>),
                      hipFuncAttributeMaxDynamicSharedMemorySize, 131072);

  // CSR extraction (deterministic, rebuilt each call)
  k_count<<<2048, 256, 0, stream>>>(sup, rcnt);
  k_scan<<<1, 1024, 0, stream>>>(rcnt, rptr);
  k_fill<<<2048, 256, 0, stream>>>(sup, rptr, cidx, cval);

  k_build_x0<<<Nn, 256, 0, stream>>>(inp, hx, x0);

  dim3 sg(RL/8, 2);   // (528 col-slabs, 2 supports)
  // gconv1
  k_spmm<false><<<sg, 256, 131072, stream>>>(x0, nullptr, y1, rptr, cidx, cval);
  k_spmm<true ><<<sg, 256, 131072, stream>>>(y1, x0,      y2, rptr, cidx, cval);
  k_gemm1<<<Nn, 256, 0, stream>>>(x0, y1, y2, ruW, ruB, hx, x0, ubuf);
  // gconv2 (x0 state slots now hold r*hx)
  k_spmm<false><<<sg, 256, 131072, stream>>>(x0, nullptr, y1, rptr, cidx, cval);
  k_spmm<true ><<<sg, 256, 131072, stream>>>(y1, x0,      y2, rptr, cidx, cval);
  k_gemm2<<<Nn, 256, 0, stream>>>(x0, y1, y2, gW, gB, hx, ubuf, out);
}

// Round 2
// 2185.180 us; speedup vs baseline: 2.0603x; 2.0603x over previous
//
#include <hip/hip_runtime.h>
#include <math.h>
#include <stdint.h>

#define Bb 64
#define Nn 4096
#define Uu 64
#define RL 4224                         // 64*66
#define NU (Nn*Uu)
#define MATSZ ((size_t)Nn*(size_t)RL)   // elements per feature matrix
#define CAP 524288
#define XSTR 360                        // K-stride (bf16) in gemm LDS, pad of 352

typedef __attribute__((ext_vector_type(8))) short short8;
typedef __attribute__((ext_vector_type(4))) float f32x4;
typedef unsigned int uint;
typedef unsigned short ushort;

__device__ inline uint f2bf(float f){ uint u=__float_as_uint(f); u += 0x7fffu + ((u>>16)&1u); return u>>16; }
__device__ inline uint pack2(float a,float b){
  uint ua=__float_as_uint(a); ua+=0x7fffu+((ua>>16)&1u);
  uint ub=__float_as_uint(b); ub+=0x7fffu+((ub>>16)&1u);
  return (ua>>16)|(ub&0xffff0000u);
}

// ---------------- CSR build from dense supports ----------------
__global__ __launch_bounds__(256) void k_count(const float* __restrict__ sup, int* __restrict__ cnt) {
  const int lane = threadIdx.x & 63;
  const int row = blockIdx.x * 4 + (threadIdx.x >> 6);
  const float* rp = sup + (size_t)row * Nn;
  int c = 0;
  for (int j = lane; j < Nn; j += 64) c += (rp[j] != 0.0f) ? 1 : 0;
  for (int off = 32; off > 0; off >>= 1) c += __shfl_down(c, off, 64);
  if (lane == 0) cnt[row] = c;
}

__global__ __launch_bounds__(1024) void k_scan(const int* __restrict__ cnt, int* __restrict__ ptr) {
  __shared__ int sums[1024];
  const int t = threadIdx.x;
  int loc[8]; int s = 0;
  for (int i = 0; i < 8; ++i) { loc[i] = cnt[t*8+i]; s += loc[i]; }
  sums[t] = s;
  __syncthreads();
  for (int off = 1; off < 1024; off <<= 1) {
    int v = (t >= off) ? sums[t-off] : 0;
    __syncthreads();
    sums[t] += v;
    __syncthreads();
  }
  int ex = (t == 0) ? 0 : sums[t-1];
  for (int i = 0; i < 8; ++i) { ptr[t*8+i] = ex; ex += loc[i]; }
  if (t == 1023) ptr[8192] = ex;
}

// packed CSR entry: (bf16(value)<<16) | col_index
__global__ __launch_bounds__(256) void k_fill(const float* __restrict__ sup, const int* __restrict__ ptr,
                                              uint* __restrict__ pk) {
  const int lane = threadIdx.x & 63;
  const int row = blockIdx.x * 4 + (threadIdx.x >> 6);
  const float* rp = sup + (size_t)row * Nn;
  const int base = ptr[row];
  const unsigned long long lt = (1ull << lane) - 1ull;
  int off = 0;
  for (int j0 = 0; j0 < Nn; j0 += 64) {
    float v = rp[j0 + lane];
    unsigned long long m = __ballot(v != 0.0f);
    if (v != 0.0f) {
      int pos = base + off + (int)__popcll(m & lt);
      pk[pos] = (f2bf(v) << 16) | (uint)(j0 + lane);
    }
    off += (int)__popcll(m);
  }
}

// ---------------- x0 = [inputs | hx] bf16 in [n][b][f] ----------------
__global__ __launch_bounds__(256) void k_bx0(const float* __restrict__ inp, const float* __restrict__ hx,
                                             ushort* __restrict__ x0) {
  const int n = blockIdx.x;
  for (int idx = threadIdx.x; idx < RL; idx += 256) {
    const int b = idx / 66, f = idx - b*66;
    float v = (f < 2) ? inp[(size_t)b*(size_t)(Nn*2) + (size_t)n*2 + f]
                      : hx[(size_t)b*(size_t)NU + (size_t)n*Uu + (f - 2)];
    x0[(size_t)n*RL + idx] = (ushort)f2bf(v);
  }
}

// ---------------- SpMM: y = A@x (PASS2: y = 2*A@x - xsub), bf16 LDS slab ----------------
// 16-col bf16 slab, row stride 20 (160 KiB): bank starts spread over 16 positions.
// 256-block grid, static schedule: 2 full (support,slab) units + 1/16-row tail unit.
template<bool PASS2>
__global__ __launch_bounds__(1024) void k_spmm(const ushort* __restrict__ xin, const ushort* __restrict__ xsub,
                                               ushort* __restrict__ yout, const int* __restrict__ rptr,
                                               const uint* __restrict__ pkv) {
  extern __shared__ ushort slab[];             // [4096][20], cols 0..15 used
  const int t = threadIdx.x, cg = t & 3, rs = t >> 2;   // 4 lanes per row, rs in [0,256)
  for (int uu = 0; uu < 3; ++uu) {
    int unit, r0, nit;
    if (uu < 2) { unit = blockIdx.x + uu*256; r0 = 0;                    nit = 16; }
    else        { unit = 512 + (blockIdx.x >> 4); r0 = (blockIdx.x & 15)*256; nit = 1; }
    const int s = unit / 264, sc = unit % 264, c0 = sc * 16;
    const ushort* xs = xin + (PASS2 ? (size_t)s*MATSZ : (size_t)0) + c0;
    if (uu) __syncthreads();
    for (int it = 0; it < 16; ++it) {          // stage all 4096 rows
      const int j = it*256 + rs;
      *(uint2*)&slab[j*20 + cg*4] = *(const uint2*)&xs[(size_t)j*RL + cg*4];
    }
    __syncthreads();
    const int rb = s * Nn;
    ushort* yo = yout + (size_t)s*MATSZ + c0;
    for (int it = 0; it < nit; ++it) {
      const int row = r0 + it*256 + rs;
      int p = rptr[rb + row];
      const int p1 = rptr[rb + row + 1];
      float a0 = 0.f, a1 = 0.f, a2 = 0.f, a3 = 0.f;
      for (; p < p1; ++p) {
        const uint e = pkv[p];                               // broadcast across the 4 lanes
        const float bv = __uint_as_float(e & 0xffff0000u);   // bf16 value == fp32 high bits
        const int jj = (int)(e & 0xffffu);
        const uint2 w = *(const uint2*)&slab[jj*20 + cg*4];
        a0 += bv * __uint_as_float(w.x << 16);
        a1 += bv * __uint_as_float(w.x & 0xffff0000u);
        a2 += bv * __uint_as_float(w.y << 16);
        a3 += bv * __uint_as_float(w.y & 0xffff0000u);
      }
      uint2 o;
      if (PASS2) {
        const uint2 xv = *(const uint2*)&xsub[(size_t)row*RL + c0 + cg*4];
        o.x = pack2(2.f*a0 - __uint_as_float(xv.x << 16), 2.f*a1 - __uint_as_float(xv.x & 0xffff0000u));
        o.y = pack2(2.f*a2 - __uint_as_float(xv.y << 16), 2.f*a3 - __uint_as_float(xv.y & 0xffff0000u));
      } else {
        o.x = pack2(a0, a1); o.y = pack2(a2, a3);
      }
      *(uint2*)&yo[(size_t)row*RL + cg*4] = o;
    }
  }
}

// ---------------- W pre-pack into MFMA B-fragment order (bf16) ----------------
// Wp[((t*11+kk)*64+l)*8+i] = W[kk*32+(l>>4)*8+i][t*16+(l&15)]  (zero-padded K 330->352)
__global__ __launch_bounds__(256) void k_wpack(const float* __restrict__ W1, const float* __restrict__ W2,
                                               ushort* __restrict__ Wp1, ushort* __restrict__ Wp2) {
  const int tid = blockIdx.x*256 + threadIdx.x;
  const int i = tid & 7, l = (tid >> 3) & 63;
  if (tid < 45056) {
    const int g = tid >> 9, tt = g / 11, kk = g % 11;
    const int r = kk*32 + (l>>4)*8 + i, c = tt*16 + (l & 15);
    Wp1[tid] = (r < 330) ? (ushort)f2bf(W1[(size_t)r*128 + c]) : (ushort)0;
  } else {
    const int t2 = tid - 45056;
    const int g = t2 >> 9, tt = g / 11, kk = g % 11;
    const int r = kk*32 + (l>>4)*8 + i, c = tt*16 + (l & 15);
    Wp2[t2] = (r < 330) ? (ushort)f2bf(W2[(size_t)r*64 + c]) : (ushort)0;
  }
}

// ---------------- gconv1 output GEMM (MFMA), fused sigmoid + r*hx + u ----------------
__global__ __launch_bounds__(256) void k_gemm1(const ushort* __restrict__ x0, const ushort* __restrict__ y1,
                                               const ushort* __restrict__ y2, const ushort* __restrict__ Wp,
                                               const float* __restrict__ bias, const float* __restrict__ hx,
                                               ushort* __restrict__ x0w, ushort* __restrict__ ubuf) {
  __shared__ ushort Xs[64*XSTR];                  // [b][k], k = f*5+m, padded to 352
  const int n = blockIdx.x, t = threadIdx.x;
  for (int q = t; q < 64*XSTR/4; q += 256) ((unsigned long long*)Xs)[q] = 0ull;
  __syncthreads();
  for (int m = 0; m < 5; ++m) {
    const ushort* mp;
    if (m == 0) mp = x0; else { mp = (m & 1) ? y1 : y2; if (m >= 3) mp += MATSZ; }
    mp += (size_t)n * RL;
    for (int q = t; q < RL; q += 256) {
      const int b = q / 66, f = q - b*66;
      Xs[b*XSTR + f*5 + m] = mp[q];
    }
  }
  __syncthreads();
  const int w = t >> 6, l = t & 63;
  const int b0 = w * 16;
  f32x4 acc[8];
  for (int i = 0; i < 8; ++i) acc[i] = (f32x4){0.f,0.f,0.f,0.f};
  const int arow = b0 + (l & 15), koff0 = (l >> 4) * 8;
  for (int kk = 0; kk < 11; ++kk) {
    const short8 af = *(const short8*)&Xs[arow*XSTR + kk*32 + koff0];
    #pragma unroll
    for (int tt = 0; tt < 8; ++tt) {
      const short8 bf = *(const short8*)&Wp[(((size_t)tt*11 + kk)*64 + l)*8];
      acc[tt] = __builtin_amdgcn_mfma_f32_16x16x32_bf16(af, bf, acc[tt], 0, 0, 0);
    }
  }
  const int rg = (l >> 4) * 4;
  #pragma unroll
  for (int tt = 0; tt < 8; ++tt) {
    const int o = tt*16 + (l & 15);
    const float bs = bias[o];
    #pragma unroll
    for (int r = 0; r < 4; ++r) {
      const int b = b0 + rg + r;
      const float v = acc[tt][r] + bs;
      const float sg = 1.0f / (1.0f + __expf(-v));
      if (o < Uu) {
        const float h = hx[(size_t)b*NU + (size_t)n*Uu + o];
        x0w[(size_t)n*RL + b*66 + 2 + o] = (ushort)f2bf(sg * h);
      } else {
        ubuf[(size_t)b*NU + (size_t)n*Uu + (o - Uu)] = (ushort)f2bf(sg);
      }
    }
  }
}

// ---------------- gconv2 output GEMM (MFMA), fused tanh + final gate ----------------
__global__ __launch_bounds__(256) void k_gemm2(const ushort* __restrict__ x0, const ushort* __restrict__ y1,
                                               const ushort* __restrict__ y2, const ushort* __restrict__ Wp,
                                               const float* __restrict__ bias, const float* __restrict__ hx,
                                               const ushort* __restrict__ ubuf, float* __restrict__ out) {
  __shared__ ushort Xs[64*XSTR];
  const int n = blockIdx.x, t = threadIdx.x;
  for (int q = t; q < 64*XSTR/4; q += 256) ((unsigned long long*)Xs)[q] = 0ull;
  __syncthreads();
  for (int m = 0; m < 5; ++m) {
    const ushort* mp;
    if (m == 0) mp = x0; else { mp = (m & 1) ? y1 : y2; if (m >= 3) mp += MATSZ; }
    mp += (size_t)n * RL;
    for (int q = t; q < RL; q += 256) {
      const int b = q / 66, f = q - b*66;
      Xs[b*XSTR + f*5 + m] = mp[q];
    }
  }
  __syncthreads();
  const int w = t >> 6, l = t & 63;
  const int b0 = w * 16;
  f32x4 acc[4];
  for (int i = 0; i < 4; ++i) acc[i] = (f32x4){0.f,0.f,0.f,0.f};
  const int arow = b0 + (l & 15), koff0 = (l >> 4) * 8;
  for (int kk = 0; kk < 11; ++kk) {
    const short8 af = *(const short8*)&Xs[arow*XSTR + kk*32 + koff0];
    #pragma unroll
    for (int tt = 0; tt < 4; ++tt) {
      const short8 bf = *(const short8*)&Wp[(((size_t)tt*11 + kk)*64 + l)*8];
      acc[tt] = __builtin_amdgcn_mfma_f32_16x16x32_bf16(af, bf, acc[tt], 0, 0, 0);
    }
  }
  const int rg = (l >> 4) * 4;
  #pragma unroll
  for (int tt = 0; tt < 4; ++tt) {
    const int o = tt*16 + (l & 15);
    const float bs = bias[o];
    #pragma unroll
    for (int r = 0; r < 4; ++r) {
      const int b = b0 + rg + r;
      const float c = tanhf(acc[tt][r] + bs);
      const size_t ix = (size_t)b*NU + (size_t)n*Uu + o;
      const float u = __uint_as_float(((uint)ubuf[ix]) << 16);
      const float h = hx[ix];
      out[ix] = u*h + (1.0f - u)*c;
    }
  }
}

extern "C" void kernel_launch(void* const* d_in, const int* in_sizes, int n_in,
                              void* d_out, int out_size, void* d_ws, size_t ws_size,
                              hipStream_t stream) {
  const float* inp = (const float*)d_in[0];
  const float* hx  = (const float*)d_in[1];
  const float* sup = (const float*)d_in[2];
  const float* ruW = (const float*)d_in[3];
  const float* ruB = (const float*)d_in[4];
  const float* gW  = (const float*)d_in[5];
  const float* gB  = (const float*)d_in[6];
  float* out = (float*)d_out;

  // workspace (bf16 intermediates, ~276 MB): x0 | y1[2] | y2[2] | u | Wpk | CSR
  ushort* x0   = (ushort*)d_ws;
  ushort* y1   = x0 + MATSZ;
  ushort* y2   = y1 + 2*MATSZ;
  ushort* ubuf = y2 + 2*MATSZ;
  ushort* Wp1  = ubuf + (size_t)Bb*NU;
  ushort* Wp2  = Wp1 + 45056;
  int*  rcnt = (int*)(Wp2 + 22528);
  int*  rptr = rcnt + 8192;
  uint* pkv  = (uint*)(rptr + 8200);

  hipFuncSetAttribute(reinterpret_cast<const void*>(&k_spmm<false>),
                      hipFuncAttributeMaxDynamicSharedMemorySize, 163840);
  hipFuncSetAttribute(reinterpret_cast<const void*>(&k_spmm<true>),
                      hipFuncAttributeMaxDynamicSharedMemorySize, 163840);

  k_count<<<2048, 256, 0, stream>>>(sup, rcnt);
  k_scan<<<1, 1024, 0, stream>>>(rcnt, rptr);
  k_fill<<<2048, 256, 0, stream>>>(sup, rptr, pkv);
  k_wpack<<<264, 256, 0, stream>>>(ruW, gW, Wp1, Wp2);
  k_bx0<<<Nn, 256, 0, stream>>>(inp, hx, x0);

  // gconv1
  k_spmm<false><<<256, 1024, 163840, stream>>>(x0, nullptr, y1, rptr, pkv);
  k_spmm<true ><<<256, 1024, 163840, stream>>>(y1, x0,      y2, rptr, pkv);
  k_gemm1<<<Nn, 256, 0, stream>>>(x0, y1, y2, Wp1, ruB, hx, x0, ubuf);
  // gconv2 (x0 state slots now hold bf16(r*hx))
  k_spmm<false><<<256, 1024, 163840, stream>>>(x0, nullptr, y1, rptr, pkv);
  k_spmm<true ><<<256, 1024, 163840, stream>>>(y1, x0,      y2, rptr, pkv);
  k_gemm2<<<Nn, 256, 0, stream>>>(x0, y1, y2, Wp2, gB, hx, ubuf, out);
}

// Round 3
// 1166.329 us; speedup vs baseline: 3.8601x; 1.8736x over previous
//
#include <hip/hip_runtime.h>
#include <math.h>
#include <stdint.h>

#define Bb 64
#define Nn 4096
#define Uu 64
#define RL 4224                         // 64*66
#define NU (Nn*Uu)
#define MATSZ ((size_t)Nn*(size_t)RL)   // elements per feature matrix
#define CAP 524288
#define XSTR 360                        // K-stride (bf16) in gemm LDS, pad of 352

typedef __attribute__((ext_vector_type(8))) short short8;
typedef __attribute__((ext_vector_type(4))) float f32x4;
typedef unsigned int uint;
typedef unsigned short ushort;

__device__ inline uint f2bf(float f){ uint u=__float_as_uint(f); u += 0x7fffu + ((u>>16)&1u); return u>>16; }
__device__ inline uint pack2(float a,float b){
  uint ua=__float_as_uint(a); ua+=0x7fffu+((ua>>16)&1u);
  uint ub=__float_as_uint(b); ub+=0x7fffu+((ub>>16)&1u);
  return (ua>>16)|(ub&0xffff0000u);
}
__device__ inline float blo(uint u){ return __uint_as_float(u << 16); }
__device__ inline float bhi(uint u){ return __uint_as_float(u & 0xffff0000u); }

// ---------------- CSR build from dense supports ----------------
__global__ __launch_bounds__(256) void k_count(const float* __restrict__ sup, int* __restrict__ cnt) {
  const int lane = threadIdx.x & 63;
  const int row = blockIdx.x * 4 + (threadIdx.x >> 6);
  const float* rp = sup + (size_t)row * Nn;
  int c = 0;
  for (int j = lane; j < Nn; j += 64) c += (rp[j] != 0.0f) ? 1 : 0;
  for (int off = 32; off > 0; off >>= 1) c += __shfl_down(c, off, 64);
  if (lane == 0) cnt[row] = c;
}

// exclusive scan of per-row counts rounded up to multiples of 4 (so every row's
// packed-CSR stream is 16B-aligned and a whole number of uint4 batches)
__global__ __launch_bounds__(1024) void k_scan(const int* __restrict__ cnt, int* __restrict__ ptr) {
  __shared__ int sums[1024];
  const int t = threadIdx.x;
  int loc[8]; int s = 0;
  for (int i = 0; i < 8; ++i) { loc[i] = (cnt[t*8+i] + 3) & ~3; s += loc[i]; }
  sums[t] = s;
  __syncthreads();
  for (int off = 1; off < 1024; off <<= 1) {
    int v = (t >= off) ? sums[t-off] : 0;
    __syncthreads();
    sums[t] += v;
    __syncthreads();
  }
  int ex = (t == 0) ? 0 : sums[t-1];
  for (int i = 0; i < 8; ++i) { ptr[t*8+i] = ex; ex += loc[i]; }
  if (t == 1023) ptr[8192] = ex;
}

// packed CSR entry: (bf16(value)<<16) | col_index ; rows zero-padded to 4-multiples
__global__ __launch_bounds__(256) void k_fill(const float* __restrict__ sup, const int* __restrict__ ptr,
                                              uint* __restrict__ pk) {
  const int lane = threadIdx.x & 63;
  const int row = blockIdx.x * 4 + (threadIdx.x >> 6);
  const float* rp = sup + (size_t)row * Nn;
  const int base = ptr[row];
  const unsigned long long lt = (1ull << lane) - 1ull;
  int off = 0;
  for (int j0 = 0; j0 < Nn; j0 += 64) {
    float v = rp[j0 + lane];
    unsigned long long m = __ballot(v != 0.0f);
    if (v != 0.0f) {
      int pos = base + off + (int)__popcll(m & lt);
      pk[pos] = (f2bf(v) << 16) | (uint)(j0 + lane);
    }
    off += (int)__popcll(m);
  }
  const int pad = (4 - (off & 3)) & 3;     // zero entries: bv=0 -> contribute nothing
  if (lane < pad) pk[base + off + lane] = 0u;
}

// ---------------- x0 = [inputs | hx] bf16 in [n][b][f] ----------------
__global__ __launch_bounds__(256) void k_bx0(const float* __restrict__ inp, const float* __restrict__ hx,
                                             ushort* __restrict__ x0) {
  const int n = blockIdx.x;
  for (int idx = threadIdx.x; idx < RL; idx += 256) {
    const int b = idx / 66, f = idx - b*66;
    float v = (f < 2) ? inp[(size_t)b*(size_t)(Nn*2) + (size_t)n*2 + f]
                      : hx[(size_t)b*(size_t)NU + (size_t)n*Uu + (f - 2)];
    x0[(size_t)n*RL + idx] = (ushort)f2bf(v);
  }
}

// ---------------- SpMM: y = A@x (PASS2: y = 2*A@x - xsub), bf16 LDS slab ----------------
// 16-col bf16 slab, row stride 20 ushorts (160 KiB). 256 blocks; XCD x = blockIdx&7 owns
// units [66x, 66x+66): adjacent 32B column strips stay on one XCD's L2 (line sharing).
// Inner loop: uint4 batch of 4 packed CSR entries -> 4 independent ds_read_b64 -> FMAs.
template<bool PASS2>
__global__ __launch_bounds__(1024) void k_spmm(const ushort* __restrict__ xin, const ushort* __restrict__ xsub,
                                               ushort* __restrict__ yout, const int* __restrict__ rptr,
                                               const uint* __restrict__ pkv) {
  extern __shared__ ushort slab[];             // [4096][20], cols 0..15 used
  const int t = threadIdx.x, cg = t & 3, rs = t >> 2;   // 4 lanes per row
  const int xc = blockIdx.x & 7, sl = blockIdx.x >> 3;  // XCD, slot 0..31
  for (int uu = 0; uu < 3; ++uu) {
    int unit, r0, nit;
    if (uu < 2) { unit = 66*xc + uu*32 + sl; r0 = 0;              nit = 16; }
    else        { unit = 66*xc + 64 + (sl >> 4); r0 = (sl & 15)*256; nit = 1; }
    const int s = unit / 264, sc = unit % 264, c0 = sc * 16;
    const ushort* xs = xin + (PASS2 ? (size_t)s*MATSZ : (size_t)0) + c0;
    if (uu) __syncthreads();
    for (int it = 0; it < 16; ++it) {          // stage all 4096 rows
      const int j = it*256 + rs;
      *(uint2*)&slab[j*20 + cg*4] = *(const uint2*)&xs[(size_t)j*RL + cg*4];
    }
    __syncthreads();
    const int rb = s * Nn;
    ushort* yo = yout + (size_t)s*MATSZ + c0;
    for (int it = 0; it < nit; ++it) {
      const int row = r0 + it*256 + rs;
      int p = rptr[rb + row];
      const int p1 = rptr[rb + row + 1];
      float a0 = 0.f, a1 = 0.f, a2 = 0.f, a3 = 0.f;
      for (; p < p1; p += 4) {
        const uint4 e = *(const uint4*)&pkv[p];
        const uint2 w0 = *(const uint2*)&slab[(e.x & 0xffffu)*20u + cg*4];
        const uint2 w1 = *(const uint2*)&slab[(e.y & 0xffffu)*20u + cg*4];
        const uint2 w2 = *(const uint2*)&slab[(e.z & 0xffffu)*20u + cg*4];
        const uint2 w3 = *(const uint2*)&slab[(e.w & 0xffffu)*20u + cg*4];
        const float b0 = bhi(e.x), b1 = bhi(e.y), b2 = bhi(e.z), b3 = bhi(e.w);
        a0 += b0*blo(w0.x); a1 += b0*bhi(w0.x); a2 += b0*blo(w0.y); a3 += b0*bhi(w0.y);
        a0 += b1*blo(w1.x); a1 += b1*bhi(w1.x); a2 += b1*blo(w1.y); a3 += b1*bhi(w1.y);
        a0 += b2*blo(w2.x); a1 += b2*bhi(w2.x); a2 += b2*blo(w2.y); a3 += b2*bhi(w2.y);
        a0 += b3*blo(w3.x); a1 += b3*bhi(w3.x); a2 += b3*blo(w3.y); a3 += b3*bhi(w3.y);
      }
      uint2 o;
      if (PASS2) {
        const uint2 xv = *(const uint2*)&xsub[(size_t)row*RL + c0 + cg*4];
        o.x = pack2(2.f*a0 - blo(xv.x), 2.f*a1 - bhi(xv.x));
        o.y = pack2(2.f*a2 - blo(xv.y), 2.f*a3 - bhi(xv.y));
      } else {
        o.x = pack2(a0, a1); o.y = pack2(a2, a3);
      }
      *(uint2*)&yo[(size_t)row*RL + cg*4] = o;
    }
  }
}

// ---------------- W pre-pack into MFMA B-fragment order (bf16) ----------------
__global__ __launch_bounds__(256) void k_wpack(const float* __restrict__ W1, const float* __restrict__ W2,
                                               ushort* __restrict__ Wp1, ushort* __restrict__ Wp2) {
  const int tid = blockIdx.x*256 + threadIdx.x;
  const int i = tid & 7, l = (tid >> 3) & 63;
  if (tid < 45056) {
    const int g = tid >> 9, tt = g / 11, kk = g % 11;
    const int r = kk*32 + (l>>4)*8 + i, c = tt*16 + (l & 15);
    Wp1[tid] = (r < 330) ? (ushort)f2bf(W1[(size_t)r*128 + c]) : (ushort)0;
  } else {
    const int t2 = tid - 45056;
    const int g = t2 >> 9, tt = g / 11, kk = g % 11;
    const int r = kk*32 + (l>>4)*8 + i, c = tt*16 + (l & 15);
    Wp2[t2] = (r < 330) ? (ushort)f2bf(W2[(size_t)r*64 + c]) : (ushort)0;
  }
}

// ---------------- gconv1 output GEMM (MFMA), fused sigmoid + r*hx + u ----------------
__global__ __launch_bounds__(256) void k_gemm1(const ushort* __restrict__ x0, const ushort* __restrict__ y1,
                                               const ushort* __restrict__ y2, const ushort* __restrict__ Wp,
                                               const float* __restrict__ bias, const float* __restrict__ hx,
                                               ushort* __restrict__ x0w, ushort* __restrict__ ubuf) {
  __shared__ ushort Xs[64*XSTR];                  // [b][k], k = f*5+m, padded to 352
  const int n = blockIdx.x, t = threadIdx.x;
  for (int q = t; q < 64*XSTR/4; q += 256) ((unsigned long long*)Xs)[q] = 0ull;
  __syncthreads();
  for (int m = 0; m < 5; ++m) {
    const ushort* mp;
    if (m == 0) mp = x0; else { mp = (m & 1) ? y1 : y2; if (m >= 3) mp += MATSZ; }
    mp += (size_t)n * RL;
    for (int q = t; q < RL; q += 256) {
      const int b = q / 66, f = q - b*66;
      Xs[b*XSTR + f*5 + m] = mp[q];
    }
  }
  __syncthreads();
  const int w = t >> 6, l = t & 63;
  const int b0 = w * 16;
  f32x4 acc[8];
  for (int i = 0; i < 8; ++i) acc[i] = (f32x4){0.f,0.f,0.f,0.f};
  const int arow = b0 + (l & 15), koff0 = (l >> 4) * 8;
  for (int kk = 0; kk < 11; ++kk) {
    const short8 af = *(const short8*)&Xs[arow*XSTR + kk*32 + koff0];
    #pragma unroll
    for (int tt = 0; tt < 8; ++tt) {
      const short8 bf = *(const short8*)&Wp[(((size_t)tt*11 + kk)*64 + l)*8];
      acc[tt] = __builtin_amdgcn_mfma_f32_16x16x32_bf16(af, bf, acc[tt], 0, 0, 0);
    }
  }
  const int rg = (l >> 4) * 4;
  #pragma unroll
  for (int tt = 0; tt < 8; ++tt) {
    const int o = tt*16 + (l & 15);
    const float bs = bias[o];
    #pragma unroll
    for (int r = 0; r < 4; ++r) {
      const int b = b0 + rg + r;
      const float v = acc[tt][r] + bs;
      const float sg = 1.0f / (1.0f + __expf(-v));
      if (o < Uu) {
        const float h = hx[(size_t)b*NU + (size_t)n*Uu + o];
        x0w[(size_t)n*RL + b*66 + 2 + o] = (ushort)f2bf(sg * h);
      } else {
        ubuf[(size_t)b*NU + (size_t)n*Uu + (o - Uu)] = (ushort)f2bf(sg);
      }
    }
  }
}

// ---------------- gconv2 output GEMM (MFMA), fused tanh + final gate ----------------
__global__ __launch_bounds__(256) void k_gemm2(const ushort* __restrict__ x0, const ushort* __restrict__ y1,
                                               const ushort* __restrict__ y2, const ushort* __restrict__ Wp,
                                               const float* __restrict__ bias, const float* __restrict__ hx,
                                               const ushort* __restrict__ ubuf, float* __restrict__ out) {
  __shared__ ushort Xs[64*XSTR];
  const int n = blockIdx.x, t = threadIdx.x;
  for (int q = t; q < 64*XSTR/4; q += 256) ((unsigned long long*)Xs)[q] = 0ull;
  __syncthreads();
  for (int m = 0; m < 5; ++m) {
    const ushort* mp;
    if (m == 0) mp = x0; else { mp = (m & 1) ? y1 : y2; if (m >= 3) mp += MATSZ; }
    mp += (size_t)n * RL;
    for (int q = t; q < RL; q += 256) {
      const int b = q / 66, f = q - b*66;
      Xs[b*XSTR + f*5 + m] = mp[q];
    }
  }
  __syncthreads();
  const int w = t >> 6, l = t & 63;
  const int b0 = w * 16;
  f32x4 acc[4];
  for (int i = 0; i < 4; ++i) acc[i] = (f32x4){0.f,0.f,0.f,0.f};
  const int arow = b0 + (l & 15), koff0 = (l >> 4) * 8;
  for (int kk = 0; kk < 11; ++kk) {
    const short8 af = *(const short8*)&Xs[arow*XSTR + kk*32 + koff0];
    #pragma unroll
    for (int tt = 0; tt < 4; ++tt) {
      const short8 bf = *(const short8*)&Wp[(((size_t)tt*11 + kk)*64 + l)*8];
      acc[tt] = __builtin_amdgcn_mfma_f32_16x16x32_bf16(af, bf, acc[tt], 0, 0, 0);
    }
  }
  const int rg = (l >> 4) * 4;
  #pragma unroll
  for (int tt = 0; tt < 4; ++tt) {
    const int o = tt*16 + (l & 15);
    const float bs = bias[o];
    #pragma unroll
    for (int r = 0; r < 4; ++r) {
      const int b = b0 + rg + r;
      const float c = tanhf(acc[tt][r] + bs);
      const size_t ix = (size_t)b*NU + (size_t)n*Uu + o;
      const float u = __uint_as_float(((uint)ubuf[ix]) << 16);
      const float h = hx[ix];
      out[ix] = u*h + (1.0f - u)*c;
    }
  }
}

extern "C" void kernel_launch(void* const* d_in, const int* in_sizes, int n_in,
                              void* d_out, int out_size, void* d_ws, size_t ws_size,
                              hipStream_t stream) {
  const float* inp = (const float*)d_in[0];
  const float* hx  = (const float*)d_in[1];
  const float* sup = (const float*)d_in[2];
  const float* ruW = (const float*)d_in[3];
  const float* ruB = (const float*)d_in[4];
  const float* gW  = (const float*)d_in[5];
  const float* gB  = (const float*)d_in[6];
  float* out = (float*)d_out;

  // workspace (bf16 intermediates): x0 | y1[2] | y2[2] | u | Wpk | CSR
  ushort* x0   = (ushort*)d_ws;
  ushort* y1   = x0 + MATSZ;
  ushort* y2   = y1 + 2*MATSZ;
  ushort* ubuf = y2 + 2*MATSZ;
  ushort* Wp1  = ubuf + (size_t)Bb*NU;
  ushort* Wp2  = Wp1 + 45056;
  int*  rcnt = (int*)(Wp2 + 22528);
  int*  rptr = rcnt + 8192;
  uint* pkv  = (uint*)(rptr + 8200);   // 16B-aligned; rows padded to uint4 batches

  hipFuncSetAttribute(reinterpret_cast<const void*>(&k_spmm<false>),
                      hipFuncAttributeMaxDynamicSharedMemorySize, 163840);
  hipFuncSetAttribute(reinterpret_cast<const void*>(&k_spmm<true>),
                      hipFuncAttributeMaxDynamicSharedMemorySize, 163840);

  k_count<<<2048, 256, 0, stream>>>(sup, rcnt);
  k_scan<<<1, 1024, 0, stream>>>(rcnt, rptr);
  k_fill<<<2048, 256, 0, stream>>>(sup, rptr, pkv);
  k_wpack<<<264, 256, 0, stream>>>(ruW, gW, Wp1, Wp2);
  k_bx0<<<Nn, 256, 0, stream>>>(inp, hx, x0);

  // gconv1
  k_spmm<false><<<256, 1024, 163840, stream>>>(x0, nullptr, y1, rptr, pkv);
  k_spmm<true ><<<256, 1024, 163840, stream>>>(y1, x0,      y2, rptr, pkv);
  k_gemm1<<<Nn, 256, 0, stream>>>(x0, y1, y2, Wp1, ruB, hx, x0, ubuf);
  // gconv2 (x0 state slots now hold bf16(r*hx))
  k_spmm<false><<<256, 1024, 163840, stream>>>(x0, nullptr, y1, rptr, pkv);
  k_spmm<true ><<<256, 1024, 163840, stream>>>(y1, x0,      y2, rptr, pkv);
  k_gemm2<<<Nn, 256, 0, stream>>>(x0, y1, y2, Wp2, gB, hx, ubuf, out);
}